// Round 1
// baseline (99.085 us; speedup 1.0000x reference)
//
#include <hip/hip_runtime.h>
#include <hip/hip_bf16.h>
#include <math.h>

#define NB 16
#define TQ 2048
#define TK 2048
#define DD 128
#define DVV 128

constexpr int QTILE = 64;   // q rows per block (4 waves x 16)
constexpr int KTILE = 64;   // k/v rows per iteration
constexpr int KPAD  = 8;    // pad (half elems) -> 272B row stride, bank-spread
constexpr int PPAD  = 8;    // pad for VT/P tiles -> 144B row stride

typedef __attribute__((ext_vector_type(8))) _Float16 half8;
typedef __attribute__((ext_vector_type(4))) float f32x4;

__global__ __launch_bounds__(256)
void attn_fwd(const float* __restrict__ qg, const float* __restrict__ kgl,
              const float* __restrict__ vg, const int* __restrict__ vlg,
              float* __restrict__ outg)
{
    __shared__ _Float16 Klds[KTILE][DD + KPAD];        // 64 x 136  (17408 B)
    __shared__ _Float16 VTlds[DVV][KTILE + PPAD];      // 128 x 72  (18432 B)
    __shared__ _Float16 Plds[4][16][KTILE + PPAD];     // 4 x 16 x 72 (9216 B)

    const int tid  = threadIdx.x;
    const int wid  = tid >> 6;
    const int lane = tid & 63;
    const int l15  = lane & 15;
    const int lhi  = lane >> 4;   // 0..3

    const int bid   = blockIdx.x;
    const int b     = bid & (NB - 1);
    const int qt    = bid >> 4;
    const int qbase = qt * QTILE;

    const int VL = vlg[b];

    // ---- load Q fragments, scale folded in ----
    half8 qf[4];
    {
        const float scale = 0.08838834764831845f;  // 1/sqrt(128)
        const int qrow = qbase + wid * 16 + l15;
        const float* qp = qg + (size_t)(b * TQ + qrow) * DD + lhi * 8;
#pragma unroll
        for (int c = 0; c < 4; ++c) {
            float4 f0 = *(const float4*)(qp + c * 32);
            float4 f1 = *(const float4*)(qp + c * 32 + 4);
            half8 t;
            t[0] = (_Float16)(f0.x * scale); t[1] = (_Float16)(f0.y * scale);
            t[2] = (_Float16)(f0.z * scale); t[3] = (_Float16)(f0.w * scale);
            t[4] = (_Float16)(f1.x * scale); t[5] = (_Float16)(f1.y * scale);
            t[6] = (_Float16)(f1.z * scale); t[7] = (_Float16)(f1.w * scale);
            qf[c] = t;
        }
    }

    float m_i[4] = {-INFINITY, -INFINITY, -INFINITY, -INFINITY};
    float l_i[4] = {0.f, 0.f, 0.f, 0.f};
    f32x4 o[8];
#pragma unroll
    for (int n = 0; n < 8; ++n) { f32x4 z = {0.f, 0.f, 0.f, 0.f}; o[n] = z; }

    const int nkt = (VL + KTILE - 1) / KTILE;

    for (int kt = 0; kt < nkt; ++kt) {
        const int kb = kt * KTILE;

        // ---- stage K tile: 64x128 fp32 -> fp16 LDS, coalesced float4 ----
#pragma unroll
        for (int p = 0; p < 8; ++p) {
            int idx = (p * 256 + tid) * 4;
            int row = idx >> 7;
            int col = idx & 127;
            float4 f = *(const float4*)(kgl + (size_t)(b * TK + kb + row) * DD + col);
            _Float16* dst = &Klds[row][col];
            dst[0] = (_Float16)f.x; dst[1] = (_Float16)f.y;
            dst[2] = (_Float16)f.z; dst[3] = (_Float16)f.w;
        }
        // ---- stage V transposed: VT[d][k], coalesced dword reads along d ----
        {
            const int d   = tid & 127;
            const int kg0 = (tid >> 7) * 32;
#pragma unroll
            for (int kp = 0; kp < 16; ++kp) {
                int kk = kg0 + kp * 2;
                float a0 = vg[(size_t)(b * TK + kb + kk) * DVV + d];
                float a1 = vg[(size_t)(b * TK + kb + kk + 1) * DVV + d];
                _Float16* dst = &VTlds[d][kk];
                dst[0] = (_Float16)a0; dst[1] = (_Float16)a1;
            }
        }
        __syncthreads();

        // ---- S = Q K^T  (4 subtiles of 16 cols, K=128 as 4 chunks of 32) ----
        f32x4 s[4];
#pragma unroll
        for (int ct = 0; ct < 4; ++ct) {
            f32x4 z = {0.f, 0.f, 0.f, 0.f};
            s[ct] = z;
#pragma unroll
            for (int c = 0; c < 4; ++c) {
                half8 kf = *(const half8*)&Klds[ct * 16 + l15][c * 32 + lhi * 8];
                s[ct] = __builtin_amdgcn_mfma_f32_16x16x32_f16(qf[c], kf, s[ct], 0, 0, 0);
            }
        }
        // ---- mask key cols >= VL (boundary tile only) ----
        if (kb + KTILE > VL) {
            const int colg = kb + l15;
#pragma unroll
            for (int ct = 0; ct < 4; ++ct)
                if (colg + ct * 16 >= VL) {
                    s[ct][0] = -1e30f; s[ct][1] = -1e30f;
                    s[ct][2] = -1e30f; s[ct][3] = -1e30f;
                }
        }

        // ---- online softmax (rows owned: lhi*4 + r) ----
#pragma unroll
        for (int r = 0; r < 4; ++r) {
            float mx = fmaxf(fmaxf(s[0][r], s[1][r]), fmaxf(s[2][r], s[3][r]));
            mx = fmaxf(mx, __shfl_xor(mx, 1));
            mx = fmaxf(mx, __shfl_xor(mx, 2));
            mx = fmaxf(mx, __shfl_xor(mx, 4));
            mx = fmaxf(mx, __shfl_xor(mx, 8));
            const float mnew = fmaxf(m_i[r], mx);
            const float corr = __expf(m_i[r] - mnew);
            float sum = 0.f;
#pragma unroll
            for (int ct = 0; ct < 4; ++ct) {
                float p = __expf(s[ct][r] - mnew);
                sum += p;
                Plds[wid][lhi * 4 + r][ct * 16 + l15] = (_Float16)p;
            }
            sum += __shfl_xor(sum, 1);
            sum += __shfl_xor(sum, 2);
            sum += __shfl_xor(sum, 4);
            sum += __shfl_xor(sum, 8);
            l_i[r] = l_i[r] * corr + sum;
            m_i[r] = mnew;
#pragma unroll
            for (int n = 0; n < 8; ++n) o[n][r] *= corr;
        }

        // ---- O += P V  (8 col tiles of 16, K=64 as 2 chunks of 32) ----
#pragma unroll
        for (int n = 0; n < 8; ++n) {
#pragma unroll
            for (int kc = 0; kc < 2; ++kc) {
                half8 pa = *(const half8*)&Plds[wid][l15][kc * 32 + lhi * 8];
                half8 vb = *(const half8*)&VTlds[n * 16 + l15][kc * 32 + lhi * 8];
                o[n] = __builtin_amdgcn_mfma_f32_16x16x32_f16(pa, vb, o[n], 0, 0, 0);
            }
        }
        __syncthreads();
    }

    // ---- normalize + write out (fp32) ----
#pragma unroll
    for (int r = 0; r < 4; ++r) {
        const float inv = 1.0f / l_i[r];
        const int qrow = qbase + wid * 16 + lhi * 4 + r;
        float* op = outg + (size_t)(b * TQ + qrow) * DVV + l15;
#pragma unroll
        for (int n = 0; n < 8; ++n)
            op[n * 16] = o[n][r] * inv;
    }
}

extern "C" void kernel_launch(void* const* d_in, const int* in_sizes, int n_in,
                              void* d_out, int out_size, void* d_ws, size_t ws_size,
                              hipStream_t stream) {
    const float* q  = (const float*)d_in[0];
    const float* k  = (const float*)d_in[1];
    const float* v  = (const float*)d_in[2];
    const int*   vl = (const int*)d_in[3];
    float* out = (float*)d_out;

    dim3 grid(NB * (TQ / QTILE));
    dim3 block(256);
    hipLaunchKernelGGL(attn_fwd, grid, block, 0, stream, q, k, v, vl, out);
}

// Round 2
// 90.386 us; speedup vs baseline: 1.0962x; 1.0962x over previous
//
#include <hip/hip_runtime.h>
#include <math.h>

#define NB 16
#define TQ 2048
#define TK 2048
#define DD 128
#define DVV 128

constexpr int QTILE = 64;   // q rows per block (4 waves x 16)
constexpr int KTILE = 64;   // k/v rows per iteration

#define KSTR (DD + 8)       // 136 halfs = 272B row stride
#define VSTR (KTILE + 8)    // 72 halfs = 144B
#define PSTR (KTILE + 8)    // 72 halfs = 144B

typedef __attribute__((ext_vector_type(8))) _Float16 half8;
typedef __attribute__((ext_vector_type(4))) _Float16 half4;
typedef __attribute__((ext_vector_type(2))) _Float16 half2v;
typedef __attribute__((ext_vector_type(4))) float f32x4;

__device__ inline float fast_exp2(float x) {
#if __has_builtin(__builtin_amdgcn_exp2f)
    return __builtin_amdgcn_exp2f(x);
#else
    return exp2f(x);
#endif
}

__global__ __launch_bounds__(256)
void attn_fwd(const float* __restrict__ qg, const float* __restrict__ kgl,
              const float* __restrict__ vg, const int* __restrict__ vlg,
              float* __restrict__ outg)
{
    __shared__ _Float16 Klds[KTILE][KSTR];       // 17408 B
    __shared__ _Float16 VTlds[DVV][VSTR];        // 18432 B
    __shared__ _Float16 Plds[4][16][PSTR];       //  9216 B

    const int tid  = threadIdx.x;
    const int wid  = tid >> 6;
    const int lane = tid & 63;
    const int l15  = lane & 15;
    const int lhi  = lane >> 4;

    const int bid   = blockIdx.x;
    const int b     = bid & (NB - 1);
    const int qbase = (bid >> 4) * QTILE;

    const int VL  = vlg[b];
    const int nkt = (VL + KTILE - 1) / KTILE;

    const float* kbase = kgl + (size_t)b * TK * DD;
    const float* vbase = vg  + (size_t)b * TK * DVV;

    // ---- Q fragments, scale * log2e folded (softmax runs in log2 domain) ----
    half8 qf[4];
    {
        const float scale = 0.08838834764831845f * 1.4426950408889634f;
        const int qrow = qbase + wid * 16 + l15;
        const float* qp = qg + (size_t)(b * TQ + qrow) * DD + lhi * 8;
#pragma unroll
        for (int c = 0; c < 4; ++c) {
            float4 f0 = *(const float4*)(qp + c * 32);
            float4 f1 = *(const float4*)(qp + c * 32 + 4);
            half8 t;
            t[0] = (_Float16)(f0.x * scale); t[1] = (_Float16)(f0.y * scale);
            t[2] = (_Float16)(f0.z * scale); t[3] = (_Float16)(f0.w * scale);
            t[4] = (_Float16)(f1.x * scale); t[5] = (_Float16)(f1.y * scale);
            t[6] = (_Float16)(f1.z * scale); t[7] = (_Float16)(f1.w * scale);
            qf[c] = t;
        }
    }

    // ---- staging geometry ----
    const int krow0 = tid >> 5;          // K row = krow0 + p*8
    const int kcol  = (tid * 4) & 127;
    const int vd    = tid & 127;         // V: d-major coalesced dword loads
    const int vk0   = (tid >> 7) * 32;
    const int va    = (vd >> 3) & 7;     // k-rotation: 8-way -> 2-way LDS write conflicts

    float4 kreg[8];
    float  vr0[16], vr1[16];

    auto issue_stage = [&](int kb) {
#pragma unroll
        for (int p = 0; p < 8; ++p)
            kreg[p] = *(const float4*)(kbase + (size_t)(kb + krow0 + p * 8) * DD + kcol);
#pragma unroll
        for (int kp = 0; kp < 16; ++kp) {
            int kk = vk0 + 2 * ((kp + va) & 15);
            vr0[kp] = vbase[(size_t)(kb + kk)     * DVV + vd];
            vr1[kp] = vbase[(size_t)(kb + kk + 1) * DVV + vd];
        }
    };
    auto write_stage = [&]() {
#pragma unroll
        for (int p = 0; p < 8; ++p) {
            half4 h;
            h[0] = (_Float16)kreg[p].x; h[1] = (_Float16)kreg[p].y;
            h[2] = (_Float16)kreg[p].z; h[3] = (_Float16)kreg[p].w;
            *(half4*)&Klds[krow0 + p * 8][kcol] = h;
        }
#pragma unroll
        for (int kp = 0; kp < 16; ++kp) {
            int kk = vk0 + 2 * ((kp + va) & 15);
            half2v h; h[0] = (_Float16)vr0[kp]; h[1] = (_Float16)vr1[kp];
            *(half2v*)&VTlds[vd][kk] = h;
        }
    };

    float m_i = -INFINITY, l_i = 0.f;
    f32x4 o[8];
#pragma unroll
    for (int n = 0; n < 8; ++n) { f32x4 z = {0.f, 0.f, 0.f, 0.f}; o[n] = z; }

    // prologue: stage tile 0
    issue_stage(0);
    write_stage();
    __syncthreads();

    for (int t = 0; t < nkt; ++t) {
        const int kb = t * KTILE;
        const bool pre = (t + 1 < nkt);
        if (pre) issue_stage(kb + KTILE);   // overlap HBM latency with compute

        // ---- S^T = K Q^T : rows = k (lhi*4+r + ct*16), cols = q (l15) ----
        f32x4 s[4];
#pragma unroll
        for (int ct = 0; ct < 4; ++ct) {
            f32x4 z = {0.f, 0.f, 0.f, 0.f};
            s[ct] = z;
#pragma unroll
            for (int c = 0; c < 4; ++c) {
                half8 kf = *(const half8*)&Klds[ct * 16 + l15][c * 32 + lhi * 8];
                s[ct] = __builtin_amdgcn_mfma_f32_16x16x32_f16(kf, qf[c], s[ct], 0, 0, 0);
            }
        }
        // ---- mask: k rows >= VL (boundary tile only) ----
        if (kb + KTILE > VL) {
#pragma unroll
            for (int ct = 0; ct < 4; ++ct) {
                const int kg = kb + ct * 16 + lhi * 4;
#pragma unroll
                for (int r = 0; r < 4; ++r)
                    if (kg + r >= VL) s[ct][r] = -1e30f;
            }
        }

        // ---- per-lane online softmax (q = l15): 16 in-lane + 2 shuffles ----
        float mx = s[0][0];
#pragma unroll
        for (int ct = 0; ct < 4; ++ct)
#pragma unroll
            for (int r = 0; r < 4; ++r) mx = fmaxf(mx, s[ct][r]);
        mx = fmaxf(mx, __shfl_xor(mx, 16));
        mx = fmaxf(mx, __shfl_xor(mx, 32));

        const bool skip = __all(mx <= m_i + 8.0f);   // defer-max (log2 domain)
        const float mnew = skip ? m_i : fmaxf(m_i, mx);

        float p[16];
        float sum = 0.f;
#pragma unroll
        for (int ct = 0; ct < 4; ++ct)
#pragma unroll
            for (int r = 0; r < 4; ++r) {
                float e = fast_exp2(s[ct][r] - mnew);
                p[ct * 4 + r] = e;
                sum += e;
            }
        sum += __shfl_xor(sum, 16);
        sum += __shfl_xor(sum, 32);

        // write P^T-layout [q][k]: 4 contiguous halfs per ct (one b64 each)
#pragma unroll
        for (int ct = 0; ct < 4; ++ct) {
            half4 ph;
            ph[0] = (_Float16)p[ct * 4 + 0]; ph[1] = (_Float16)p[ct * 4 + 1];
            ph[2] = (_Float16)p[ct * 4 + 2]; ph[3] = (_Float16)p[ct * 4 + 3];
            *(half4*)&Plds[wid][l15][ct * 16 + lhi * 4] = ph;
        }

        if (skip) {
            l_i += sum;
        } else {
            const float corr = fast_exp2(m_i - mnew);
            l_i = l_i * corr + sum;
            m_i = mnew;
            float cr[4];
#pragma unroll
            for (int r = 0; r < 4; ++r)
                cr[r] = __shfl(corr, (lane & 48) | (lhi * 4 + r));
#pragma unroll
            for (int n = 0; n < 8; ++n)
#pragma unroll
                for (int r = 0; r < 4; ++r) o[n][r] *= cr[r];
        }

        // ---- O += P V ----
        half8 pa0 = *(const half8*)&Plds[wid][l15][lhi * 8];
        half8 pa1 = *(const half8*)&Plds[wid][l15][32 + lhi * 8];
#pragma unroll
        for (int n = 0; n < 8; ++n) {
            half8 vb0 = *(const half8*)&VTlds[n * 16 + l15][lhi * 8];
            half8 vb1 = *(const half8*)&VTlds[n * 16 + l15][32 + lhi * 8];
            o[n] = __builtin_amdgcn_mfma_f32_16x16x32_f16(pa0, vb0, o[n], 0, 0, 0);
            o[n] = __builtin_amdgcn_mfma_f32_16x16x32_f16(pa1, vb1, o[n], 0, 0, 0);
        }

        __syncthreads();
        if (pre) write_stage();              // vmcnt drained here, not in compute
        __syncthreads();
    }

    // ---- epilogue: broadcast l to o-row owners, normalize, store ----
    float li4[4];
#pragma unroll
    for (int r = 0; r < 4; ++r) {
        float lr = __shfl(l_i, (lane & 48) | (lhi * 4 + r));
        li4[r] = 1.0f / lr;
    }
#pragma unroll
    for (int r = 0; r < 4; ++r) {
        const int qrow = qbase + wid * 16 + lhi * 4 + r;
        float* op = outg + (size_t)(b * TQ + qrow) * DVV + l15;
#pragma unroll
        for (int n = 0; n < 8; ++n)
            op[n * 16] = o[n][r] * li4[r];
    }
}

extern "C" void kernel_launch(void* const* d_in, const int* in_sizes, int n_in,
                              void* d_out, int out_size, void* d_ws, size_t ws_size,
                              hipStream_t stream) {
    const float* q  = (const float*)d_in[0];
    const float* k  = (const float*)d_in[1];
    const float* v  = (const float*)d_in[2];
    const int*   vl = (const int*)d_in[3];
    float* out = (float*)d_out;

    dim3 grid(NB * (TQ / QTILE));
    dim3 block(256);
    hipLaunchKernelGGL(attn_fwd, grid, block, 0, stream, q, k, v, vl, out);
}